// Round 16
// baseline (885.167 us; speedup 1.0000x reference)
//
#include <hip/hip_runtime.h>
#include <math.h>

#define BB 16384
#define P 20
#define NT 512

typedef short v8s __attribute__((ext_vector_type(8)));
typedef _Float16 v8h __attribute__((ext_vector_type(8)));
typedef float f32x4 __attribute__((ext_vector_type(4)));
typedef float f32x16 __attribute__((ext_vector_type(16)));

// ---- static device buffers: referenced ONLY inside device code. ----
// +4096 pad: knn_mfma/agg_mfma read rows u=20..31 of the last samples (garbage,
// multiplied by zero-padded M columns / never stored).
#define NELEM ((size_t)BB * P * 320)          // 209.7 MB each
__device__ unsigned int g_C[3][P * P];
__device__ __align__(16) unsigned short g_bufA[NELEM + 4096];  // z1 / y2(bf16) / y3(bf16) / h4
__device__ __align__(16) unsigned short g_bufB[NELEM + 4096];  // h1 / h2 / h3f
__device__ __align__(16) unsigned short g_W1b[320 * 128];
__device__ __align__(16) unsigned short g_W2b[128 * 320];
__device__ __align__(16) unsigned short g_W3b[64 * 128];
__device__ __align__(16) unsigned short g_W4b[112 * 1024];
__device__ __align__(16) float g_b1p[320];
__device__ __align__(16) float g_b2p[128];
__device__ __align__(16) float g_b3p[64];
__device__ __align__(16) float g_b4p[112];

__device__ inline float bf2f(unsigned short u) {
    union { unsigned int i; float f; } c; c.i = ((unsigned int)u) << 16; return c.f;
}
__device__ inline unsigned short f2bf(float f) {
    union { float f; unsigned int i; } c; c.f = f;
    unsigned int u = c.i + 0x7fffu + ((c.i >> 16) & 1u);  // RNE (no NaN in data)
    return (unsigned short)(u >> 16);
}

// Pad+convert weights/biases to bf16 (zero pads -> pad outputs relu(0+0)=0).
// Also zeroes g_C (merged former zero_C launch — runs before any knn kernel).
__global__ void prep_kernel(const float* __restrict__ W1, const float* __restrict__ b1,
                            const float* __restrict__ W2, const float* __restrict__ b2,
                            const float* __restrict__ W3, const float* __restrict__ b3,
                            const float* __restrict__ W4, const float* __restrict__ b4) {
    const int stride = gridDim.x * blockDim.x;
    const int id = blockIdx.x * blockDim.x + threadIdx.x;
    for (int i = id; i < 3 * P * P; i += stride) g_C[i / (P * P)][i % (P * P)] = 0u;
    for (int i = id; i < 320 * 128; i += stride) { int n = i >> 7, k = i & 127;
        g_W1b[i] = (n < 300) ? f2bf(W1[n * 128 + k]) : 0; }
    for (int i = id; i < 128 * 320; i += stride) { int n = i / 320, k = i - n * 320;
        g_W2b[i] = (n < 100 && k < 300) ? f2bf(W2[n * 300 + k]) : 0; }
    for (int i = id; i < 64 * 128; i += stride) { int n = i >> 7, k = i & 127;
        g_W3b[i] = (n < 50 && k < 100) ? f2bf(W3[n * 100 + k]) : 0; }
    for (int i = id; i < 112 * 1024; i += stride) { int n = i >> 10, k = i & 1023;
        g_W4b[i] = (n < 100 && k < 1000) ? f2bf(W4[n * 1000 + k]) : 0; }
    for (int i = id; i < 320; i += stride) g_b1p[i] = (i < 300) ? b1[i] : 0.f;
    for (int i = id; i < 128; i += stride) g_b2p[i] = (i < 100) ? b2[i] : 0.f;
    for (int i = id; i < 64;  i += stride) g_b3p[i] = (i < 50)  ? b3[i] : 0.f;
    for (int i = id; i < 112; i += stride) g_b4p[i] = (i < 100) ? b4[i] : 0.f;
}

// ---------------- kNN layer 1: MFMA Gram on fp16 hi/lo split (verified r8) --
__global__ __launch_bounds__(NT)
void knn1_mfma_kernel(const float* __restrict__ x) {
    __shared__ float Gs[8][P * 21];
    __shared__ unsigned int hist[P * P];
    const int t = threadIdx.x, w = t >> 6, lane = t & 63;
    const int m31 = lane & 31, half = lane >> 5;
    const int mrow = (m31 < P) ? m31 : (P - 1);
    for (int i = t; i < P * P; i += NT) hist[i] = 0;
    for (int pass = 0; pass < 2; ++pass) {
        const size_t s = (size_t)blockIdx.x * 16 + pass * 8 + w;
        const float* rp = x + s * (size_t)(P * 128) + (size_t)mrow * 128 + half * 8;
        f32x16 acc;
#pragma unroll
        for (int i = 0; i < 16; ++i) acc[i] = 0.f;
#pragma unroll
        for (int ks = 0; ks < 8; ++ks) {
            float4 f0 = *(const float4*)(rp + ks * 16);
            float4 f1 = *(const float4*)(rp + ks * 16 + 4);
            float fv[8] = {f0.x, f0.y, f0.z, f0.w, f1.x, f1.y, f1.z, f1.w};
            v8h hi, lo;
#pragma unroll
            for (int j = 0; j < 8; ++j) {
                _Float16 hv = (_Float16)fv[j];
                hi[j] = hv;
                lo[j] = (_Float16)(fv[j] - (float)hv);
            }
            acc = __builtin_amdgcn_mfma_f32_32x32x16_f16(hi, hi, acc, 0, 0, 0);
            acc = __builtin_amdgcn_mfma_f32_32x32x16_f16(hi, lo, acc, 0, 0, 0);
            acc = __builtin_amdgcn_mfma_f32_32x32x16_f16(lo, hi, acc, 0, 0, 0);
            acc = __builtin_amdgcn_mfma_f32_32x32x16_f16(lo, lo, acc, 0, 0, 0);
        }
        float* G = &Gs[w][0];
        if (m31 < P) {
#pragma unroll
            for (int r = 0; r < 16; ++r) {
                int row = (r & 3) + 8 * (r >> 2) + 4 * half;
                if (row < P) G[row * 21 + m31] = acc[r];
            }
        }
        __syncthreads();
        if (lane < P) {
            const int p = lane;
            float d2[P];
            const float gpp = G[p * 21 + p];
#pragma unroll
            for (int u = 0; u < P; ++u)
                d2[u] = (u == p) ? 0.f : gpp + G[u * 21 + u] - 2.f * G[p * 21 + u];
            float pv = -3.0e38f; int pi = -1;
            for (int it = 0; it < 6; ++it) {
                float best = 3.0e38f; int bq = 0;
#pragma unroll
                for (int u = 0; u < P; ++u) {
                    float vu = d2[u];
                    bool cand = (vu > pv) || (vu == pv && u > pi);
                    if (cand && vu < best) { best = vu; bq = u; }
                }
                if (it > 0) atomicAdd(&hist[bq * P + p], 1u);
                pv = best; pi = bq;
            }
        }
        __syncthreads();
    }
    if (t < P * P && hist[t]) atomicAdd(&g_C[0][t], hist[t]);
}

// ---------------- kNN via MFMA Gram: G = Z Z^T per sample (verified r6) -----
template<int D, int CIDX>
__global__ __launch_bounds__(NT)
void knn_mfma_kernel() {
    __shared__ float Gs[8][P * 21];
    __shared__ unsigned int hist[P * P];
    const int t = threadIdx.x, w = t >> 6, lane = t & 63;
    const int m31 = lane & 31, half = lane >> 5;
    for (int i = t; i < P * P; i += NT) hist[i] = 0;
    for (int pass = 0; pass < 2; ++pass) {
        const size_t s = (size_t)blockIdx.x * 16 + pass * 8 + w;
        const unsigned short* rp = g_bufB + s * (P * D) + (size_t)m31 * D + half * 8;
        f32x16 acc;
#pragma unroll
        for (int i = 0; i < 16; ++i) acc[i] = 0.f;
        for (int ks = 0; ks < D / 16; ++ks) {
            v8s z = *(const v8s*)(rp + ks * 16);
            acc = __builtin_amdgcn_mfma_f32_32x32x16_bf16(z, z, acc, 0, 0, 0);
        }
        float* G = &Gs[w][0];
        if (m31 < P) {
#pragma unroll
            for (int r = 0; r < 16; ++r) {
                int row = (r & 3) + 8 * (r >> 2) + 4 * half;
                if (row < P) G[row * 21 + m31] = acc[r];
            }
        }
        __syncthreads();
        if (lane < P) {
            const int p = lane;
            float d2[P];
            const float gpp = G[p * 21 + p];
#pragma unroll
            for (int u = 0; u < P; ++u)
                d2[u] = (u == p) ? 0.f : gpp + G[u * 21 + u] - 2.f * G[p * 21 + u];
            float pv = -3.0e38f; int pi = -1;
            for (int it = 0; it < 6; ++it) {
                float best = 3.0e38f; int bq = 0;
#pragma unroll
                for (int u = 0; u < P; ++u) {
                    float vu = d2[u];
                    bool cand = (vu > pv) || (vu == pv && u > pi);
                    if (cand && vu < best) { best = vu; bq = u; }
                }
                if (it > 0) atomicAdd(&hist[bq * P + p], 1u);
                pv = best; pi = bq;
            }
        }
        __syncthreads();
    }
    if (t < P * P && hist[t]) atomicAdd(&g_C[CIDX][t], hist[t]);
}

// compute_M for 512-thread blocks (strided loops)
__device__ inline void compute_M_512(const unsigned int* __restrict__ Cg,
                                     float* Ms, float* dinv, int t) {
    for (int i = t; i < P * P; i += 512) Ms[i] = (float)Cg[i];
    __syncthreads();
    if (t < P) {
        float deg = 1.f;
        for (int u = 0; u < P; ++u) deg += Ms[t * P + u];
        dinv[t] = 1.f / sqrtf(deg);
    }
    __syncthreads();
    for (int i = t; i < P * P; i += 512) {
        int v = i / P, u = i - v * P;
        float m = dinv[v] * Ms[i] * dinv[u];
        if (v == u) m += dinv[v] * dinv[v];
        Ms[i] = m;
    }
    __syncthreads();
}

// ---------------- agg via MFMA (verified r13): z1 = M @ x, layer 1 only -----
template<int D, int CIDX>
__global__ __launch_bounds__(512)
void agg_mfma_kernel(const float* __restrict__ xin) {
    constexpr int NCB = D / 32;              // 32-col blocks
    __shared__ float Ms[P * P];
    __shared__ float dinv[P];
    const int t = threadIdx.x, w = t >> 6, lane = t & 63;
    const int n31 = lane & 31, half = lane >> 5;
    compute_M_512(g_C[CIDX], Ms, dinv, t);
    v8s mhi[2], mlo[2];
#pragma unroll
    for (int kc = 0; kc < 2; ++kc)
#pragma unroll
        for (int j = 0; j < 8; ++j) {
            const int u = kc * 16 + half * 8 + j;
            const int v = n31;
            const float m = (v < P && u < P) ? Ms[v * P + u] : 0.f;
            const unsigned short h16 = f2bf(m);
            mhi[kc][j] = (short)h16;
            mlo[kc][j] = (short)f2bf(m - bf2f(h16));
        }
    const size_t s = (size_t)blockIdx.x * 8 + w;
    unsigned short* zout = g_bufA + s * (size_t)(P * D);
    const float* xr = xin + s * (size_t)(P * D);
#pragma unroll
    for (int cb = 0; cb < NCB; ++cb) {
        v8s bh0, bl0, bh1, bl1;
#pragma unroll
        for (int j = 0; j < 8; ++j) {
            const int u0 = half * 8 + j;                 // < 16, always valid
            int u1 = 16 + half * 8 + j; if (u1 > P - 1) u1 = P - 1;  // clamp
            const float x0 = xr[(size_t)u0 * D + cb * 32 + n31];
            const float x1 = xr[(size_t)u1 * D + cb * 32 + n31];
            const unsigned short h0 = f2bf(x0), h1 = f2bf(x1);
            bh0[j] = (short)h0; bl0[j] = (short)f2bf(x0 - bf2f(h0));
            bh1[j] = (short)h1; bl1[j] = (short)f2bf(x1 - bf2f(h1));
        }
        f32x16 acc;
#pragma unroll
        for (int i = 0; i < 16; ++i) acc[i] = 0.f;
        acc = __builtin_amdgcn_mfma_f32_32x32x16_bf16(mhi[0], bh0, acc, 0, 0, 0);
        acc = __builtin_amdgcn_mfma_f32_32x32x16_bf16(mhi[0], bl0, acc, 0, 0, 0);
        acc = __builtin_amdgcn_mfma_f32_32x32x16_bf16(mlo[0], bh0, acc, 0, 0, 0);
        acc = __builtin_amdgcn_mfma_f32_32x32x16_bf16(mlo[0], bl0, acc, 0, 0, 0);
        acc = __builtin_amdgcn_mfma_f32_32x32x16_bf16(mhi[1], bh1, acc, 0, 0, 0);
        acc = __builtin_amdgcn_mfma_f32_32x32x16_bf16(mhi[1], bl1, acc, 0, 0, 0);
        acc = __builtin_amdgcn_mfma_f32_32x32x16_bf16(mlo[1], bh1, acc, 0, 0, 0);
        acc = __builtin_amdgcn_mfma_f32_32x32x16_bf16(mlo[1], bl1, acc, 0, 0, 0);
#pragma unroll
        for (int r = 0; r < 16; ++r) {
            const int row = (r & 3) + 8 * (r >> 2) + 4 * half;
            if (row < P)
                zout[(size_t)row * D + cb * 32 + n31] = f2bf(acc[r]);
        }
    }
}

// ---------------- agg-after-gemm, bf16 y (verified r18) ---------------------
template<int D, int CIDX, bool FLATOUT>
__global__ __launch_bounds__(512)
void agg_out_kernel() {
    constexpr int NCB = D / 32;
    __shared__ float Ms[P * P];
    __shared__ float dinv[P];
    const int t = threadIdx.x, w = t >> 6, lane = t & 63;
    const int n31 = lane & 31, half = lane >> 5;
    const float* __restrict__ bp = (CIDX == 1) ? g_b2p : g_b3p;
    compute_M_512(g_C[CIDX], Ms, dinv, t);
    v8s mhi[2], mlo[2];
#pragma unroll
    for (int kc = 0; kc < 2; ++kc)
#pragma unroll
        for (int j = 0; j < 8; ++j) {
            const int u = kc * 16 + half * 8 + j;
            const int v = n31;
            const float m = (v < P && u < P) ? Ms[v * P + u] : 0.f;
            const unsigned short h16 = f2bf(m);
            mhi[kc][j] = (short)h16;
            mlo[kc][j] = (short)f2bf(m - bf2f(h16));
        }
    const size_t s = (size_t)blockIdx.x * 8 + w;
    const unsigned short* yr = g_bufA + s * (size_t)(P * D);
#pragma unroll
    for (int cb = 0; cb < NCB; ++cb) {
        v8s b0, b1;
#pragma unroll
        for (int j = 0; j < 8; ++j) {
            const int u0 = half * 8 + j;                 // < 16, always valid
            int u1 = 16 + half * 8 + j; if (u1 > P - 1) u1 = P - 1;  // clamp
            b0[j] = (short)yr[(size_t)u0 * D + cb * 32 + n31];
            b1[j] = (short)yr[(size_t)u1 * D + cb * 32 + n31];
        }
        f32x16 acc;
#pragma unroll
        for (int i = 0; i < 16; ++i) acc[i] = 0.f;
        acc = __builtin_amdgcn_mfma_f32_32x32x16_bf16(mhi[0], b0, acc, 0, 0, 0);
        acc = __builtin_amdgcn_mfma_f32_32x32x16_bf16(mlo[0], b0, acc, 0, 0, 0);
        acc = __builtin_amdgcn_mfma_f32_32x32x16_bf16(mhi[1], b1, acc, 0, 0, 0);
        acc = __builtin_amdgcn_mfma_f32_32x32x16_bf16(mlo[1], b1, acc, 0, 0, 0);
        const float bv = bp[cb * 32 + n31];
#pragma unroll
        for (int r = 0; r < 16; ++r) {
            const int row = (r & 3) + 8 * (r >> 2) + 4 * half;
            if (row < P) {
                const float val = fmaxf(acc[r] + bv, 0.f);
                if (FLATOUT) {
                    const int d = cb * 32 + n31;
                    if (d < 50)
                        g_bufB[s * 1024 + (size_t)row * 50 + d] = f2bf(val);
                } else {
                    g_bufB[(s * (size_t)P + row) * D + cb * 32 + n31] = f2bf(val);
                }
            }
        }
    }
}

// ---------------- gemm2' (r14 structure): y2 = h1 @ W2^T, bf16 raw out ------
__global__ __launch_bounds__(256)
void gemm2_kernel() {
    constexpr int KL = 72;                   // padded LDS row, elems
    __shared__ __align__(16) unsigned short As[128 * KL];
    __shared__ __align__(16) unsigned short Wsh[128 * KL];
    const int t = threadIdx.x, w = t >> 6, lane = t & 63;
    const int m15 = lane & 15, q = lane >> 4;
    const long row0 = (long)blockIdx.x * 128;
    f32x4 acc[2][8];
#pragma unroll
    for (int zr = 0; zr < 2; ++zr)
#pragma unroll
        for (int nf = 0; nf < 8; ++nf) acc[zr][nf] = 0.f;
    for (int kc = 0; kc < 5; ++kc) {         // K chunks of 64 elems
        __syncthreads();                     // guard LDS reuse
        for (int i = t; i < 1024; i += 256) {
            const int r = i >> 3, c8 = i & 7;
            *(v8s*)&As[r * KL + c8 * 8] =
                *(const v8s*)(g_bufB + (size_t)(row0 + r) * 320 + kc * 64 + c8 * 8);
            *(v8s*)&Wsh[r * KL + c8 * 8] =
                *(const v8s*)(g_W2b + (size_t)r * 320 + kc * 64 + c8 * 8);
        }
        __syncthreads();
#pragma unroll
        for (int ks = 0; ks < 2; ++ks) {     // 32-elem MFMA sub-steps
            v8s af[2];
#pragma unroll
            for (int zr = 0; zr < 2; ++zr)
                af[zr] = *(const v8s*)&As[(w * 32 + zr * 16 + m15) * KL + ks * 32 + q * 8];
#pragma unroll
            for (int nf = 0; nf < 8; ++nf) {
                v8s wf = *(const v8s*)&Wsh[(nf * 16 + m15) * KL + ks * 32 + q * 8];
#pragma unroll
                for (int zr = 0; zr < 2; ++zr)
                    acc[zr][nf] = __builtin_amdgcn_mfma_f32_16x16x32_bf16(
                        wf, af[zr], acc[zr][nf], 0, 0, 0);
            }
        }
    }
#pragma unroll
    for (int zr = 0; zr < 2; ++zr) {
        const long m = row0 + w * 32 + zr * 16 + m15;
#pragma unroll
        for (int nf = 0; nf < 8; ++nf) {
            f32x4 c = acc[zr][nf];
            ushort4 o; o.x = f2bf(c[0]); o.y = f2bf(c[1]);
            o.z = f2bf(c[2]); o.w = f2bf(c[3]);
            *(ushort4*)(g_bufA + (size_t)m * 128 + nf * 16 + q * 4) = o;
        }
    }
}

// ---------------- streaming MFMA GEMM (r9 form; + RAWBF16 raw-bf16 out) -----
template<int Kp, int Np, int ZR, bool FLAT, int WSEL, bool ATOB, int NSPLIT,
         int KSC, int NTHR, long MROWS, bool RAWBF16>
__global__ __launch_bounds__(NTHR)
void gemm_kernel() {
    constexpr int BN = Np / NSPLIT;          // cols handled by this block
    constexpr int NF = BN / 16;
    constexpr int KS = Kp / 32;
    constexpr int CPT = KS / KSC;            // chunks per tile
    constexpr int KL = Kp + 8;               // padded LDS row (elems, 16B step)
    constexpr int NW = NTHR / 64;
    constexpr int TM = NW * ZR * 16;         // rows per tile
    constexpr long NTILE = MROWS / TM;
    static_assert(KS % KSC == 0, "KSC must divide KS");
    __shared__ __align__(16) unsigned short Ws[BN * KL];
    __shared__ __align__(16) float bs[BN];
    const unsigned short* __restrict__ Wb =
        (WSEL == 1) ? g_W1b : (WSEL == 2) ? g_W2b : (WSEL == 3) ? g_W3b : g_W4b;
    const float* __restrict__ bp =
        (WSEL == 1) ? g_b1p : (WSEL == 2) ? g_b2p : (WSEL == 3) ? g_b3p : g_b4p;
    const unsigned short* __restrict__ A = ATOB ? g_bufA : g_bufB;
    unsigned short* __restrict__ Hout = ATOB ? g_bufB : g_bufA;
    const int t = threadIdx.x, w = t >> 6, lane = t & 63;
    const int m15 = lane & 15, q = lane >> 4;
    const int n0 = blockIdx.y * BN;
    // ---- stage W slice + bias to LDS (once per block) ----
    for (int i = t; i < BN * (Kp / 8); i += NTHR) {
        int r = i / (Kp / 8), c = i - r * (Kp / 8);
        *(v8s*)(&Ws[r * KL + c * 8]) = *(const v8s*)(Wb + (size_t)(n0 + r) * Kp + c * 8);
    }
    for (int i = t; i < BN; i += NTHR) bs[i] = bp[n0 + i];
    __syncthreads();

    v8s aC[ZR][KSC], aN[ZR][KSC];
    long tile = (long)blockIdx.x;
    if (tile < NTILE) {
        const unsigned short* ab =
            A + (size_t)(tile * TM + w * (ZR * 16) + m15) * Kp + q * 8;
#pragma unroll
        for (int zr = 0; zr < ZR; ++zr)
#pragma unroll
            for (int ks = 0; ks < KSC; ++ks)
                aC[zr][ks] = *(const v8s*)(ab + (size_t)zr * 16 * Kp + ks * 32);
    }
    for (; tile < NTILE; tile += gridDim.x) {
        f32x4 acc[ZR][NF];
#pragma unroll
        for (int zr = 0; zr < ZR; ++zr)
#pragma unroll
            for (int nf = 0; nf < NF; ++nf) acc[zr][nf] = 0.f;
        for (int c = 0; c < CPT; ++c) {
            // issue next chunk's A loads before consuming the current chunk
            const long ntile = (c + 1 < CPT) ? tile : tile + (long)gridDim.x;
            const int nk0 = (c + 1 < CPT) ? (c + 1) * KSC : 0;
            const bool hasNext = (ntile < NTILE);
            if (hasNext) {
                const unsigned short* ab =
                    A + (size_t)(ntile * TM + w * (ZR * 16) + m15) * Kp + nk0 * 32 + q * 8;
#pragma unroll
                for (int zr = 0; zr < ZR; ++zr)
#pragma unroll
                    for (int ks = 0; ks < KSC; ++ks)
                        aN[zr][ks] = *(const v8s*)(ab + (size_t)zr * 16 * Kp + ks * 32);
            }
#pragma unroll
            for (int nf = 0; nf < NF; ++nf) {
                v8s wr[KSC];
#pragma unroll
                for (int ks = 0; ks < KSC; ++ks)
                    wr[ks] = *(const v8s*)(&Ws[(nf * 16 + m15) * KL + (c * KSC + ks) * 32 + q * 8]);
#pragma unroll
                for (int ks = 0; ks < KSC; ++ks)
#pragma unroll
                    for (int zr = 0; zr < ZR; ++zr)
                        acc[zr][nf] = __builtin_amdgcn_mfma_f32_16x16x32_bf16(
                            wr[ks], aC[zr][ks], acc[zr][nf], 0, 0, 0);
            }
            if (hasNext) {
#pragma unroll
                for (int zr = 0; zr < ZR; ++zr)
#pragma unroll
                    for (int ks = 0; ks < KSC; ++ks) aC[zr][ks] = aN[zr][ks];
            }
        }
        // ---- epilogue ----
#pragma unroll
        for (int zr = 0; zr < ZR; ++zr) {
            const long m = tile * TM + w * (ZR * 16) + zr * 16 + m15;
#pragma unroll
            for (int nf = 0; nf < NF; ++nf) {
                f32x4 cc = acc[zr][nf];
                if (RAWBF16) {
                    ushort4 o; o.x = f2bf(cc[0]); o.y = f2bf(cc[1]);
                    o.z = f2bf(cc[2]); o.w = f2bf(cc[3]);
                    *(ushort4*)(Hout + (size_t)m * Np + n0 + nf * 16 + q * 4) = o;
                } else {
                    f32x4 b4 = *(const f32x4*)(&bs[nf * 16 + q * 4]);
                    float v0 = fmaxf(cc[0] + b4[0], 0.f), v1 = fmaxf(cc[1] + b4[1], 0.f);
                    float v2 = fmaxf(cc[2] + b4[2], 0.f), v3 = fmaxf(cc[3] + b4[3], 0.f);
                    if (!FLAT) {
                        ushort4 o; o.x = f2bf(v0); o.y = f2bf(v1); o.z = f2bf(v2); o.w = f2bf(v3);
                        *(ushort4*)(Hout + (size_t)m * Np + n0 + nf * 16 + q * 4) = o;
                    } else {
                        const int n0f = nf * 16 + q * 4;   // FLAT only with NSPLIT=1
                        if (n0f <= 48) {
                            const long s = m / 20; const int u = (int)(m - s * 20);
                            unsigned short* base = Hout + (size_t)s * 1024 + u * 50 + n0f;
                            unsigned int lo = (unsigned int)f2bf(v0) | ((unsigned int)f2bf(v1) << 16);
                            *(unsigned int*)(base) = lo;
                            if (n0f < 48) {
                                unsigned int hi = (unsigned int)f2bf(v2) | ((unsigned int)f2bf(v3) << 16);
                                *(unsigned int*)(base + 2) = hi;
                            }
                        }
                    }
                }
            }
        }
    }
}

// logits = W5 h4 + b5; softmax -> out. h4 in g_bufA (112-padded rows).
// 256 blocks x 64 threads -> 4x CU coverage (verified r20). One sample/thread.
__global__ __launch_bounds__(64)
void head_kernel(const float* __restrict__ W5, const float* __restrict__ b5,
                 float* __restrict__ out) {
    __shared__ float w5s[300];
    __shared__ float b5s[3];
    const int t = threadIdx.x;
    for (int i = t; i < 300; i += 64) w5s[i] = W5[i];
    if (t < 3) b5s[t] = b5[t];
    __syncthreads();
    const int s = blockIdx.x * 64 + t;
    const unsigned short* h = g_bufA + (size_t)s * 112;
    float a0 = b5s[0], a1 = b5s[1], a2 = b5s[2];
    for (int k = 0; k < 100; ++k) {
        float hv = bf2f(h[k]);
        a0 += hv * w5s[k]; a1 += hv * w5s[100 + k]; a2 += hv * w5s[200 + k];
    }
    float m = fmaxf(a0, fmaxf(a1, a2));
    float e0 = expf(a0 - m), e1 = expf(a1 - m), e2 = expf(a2 - m);
    float inv = 1.f / (e0 + e1 + e2);
    out[(size_t)s * 3 + 0] = e0 * inv;
    out[(size_t)s * 3 + 1] = e1 * inv;
    out[(size_t)s * 3 + 2] = e2 * inv;
}

extern "C" void kernel_launch(void* const* d_in, const int* in_sizes, int n_in,
                              void* d_out, int out_size, void* d_ws, size_t ws_size,
                              hipStream_t stream) {
    const float* x  = (const float*)d_in[0];
    const float* W1 = (const float*)d_in[1];
    const float* b1 = (const float*)d_in[2];
    const float* W2 = (const float*)d_in[3];
    const float* b2 = (const float*)d_in[4];
    const float* W3 = (const float*)d_in[5];
    const float* b3 = (const float*)d_in[6];
    const float* W4 = (const float*)d_in[7];
    const float* b4 = (const float*)d_in[8];
    const float* W5 = (const float*)d_in[9];
    const float* b5 = (const float*)d_in[10];
    float* out = (float*)d_out;

    prep_kernel<<<256, 256, 0, stream>>>(W1, b1, W2, b2, W3, b3, W4, b4);

    // ---- layer 1 (r9 proven split; grid.x=1024 = r14 measured best) ----
    knn1_mfma_kernel<<<BB / 16, NT, 0, stream>>>(x);                 // x -> C0
    agg_mfma_kernel<128, 0><<<BB / 8, 512, 0, stream>>>(x);          // x -> z1(A)
    gemm_kernel<128, 320, 1, false, 1, true, 2, 4, 512, 327680L, false>
        <<<dim3(1024, 2), 512, 0, stream>>>();                       // z1 -> h1(B)

    // ---- layer 2 (gemm first, bf16 y2; agg on y2) ----
    knn_mfma_kernel<320, 1><<<BB / 16, NT, 0, stream>>>();           // h1(B) -> C1
    gemm2_kernel<<<2560, 256, 0, stream>>>();                        // h1 -> y2 bf16 (A)
    agg_out_kernel<128, 1, false><<<BB / 8, 512, 0, stream>>>();     // y2 -> h2(B)

    // ---- layer 3 (gemm first, bf16 y3; agg on y3; grid 512 = r14 best) ----
    knn_mfma_kernel<128, 2><<<BB / 16, NT, 0, stream>>>();           // h2(B) -> C2
    gemm_kernel<128, 64, 2, false, 3, false, 1, 4, 256, 327680L, true>
        <<<dim3(512, 1), 256, 0, stream>>>();                        // h2 -> y3 bf16 (A)
    agg_out_kernel<64, 2, true><<<BB / 8, 512, 0, stream>>>();       // y3 -> h3f(B) FLAT

    // ---- head MLP ----
    gemm_kernel<1024, 112, 1, false, 4, false, 7, 8, 256, 16384L, false>
        <<<dim3(256, 7), 256, 0, stream>>>();                        // h3f(B) -> h4(A)
    head_kernel<<<BB / 64, 64, 0, stream>>>(W5, b5, out);
}

// Round 17
// 794.609 us; speedup vs baseline: 1.1140x; 1.1140x over previous
//
#include <hip/hip_runtime.h>
#include <math.h>

#define BB 16384
#define P 20
#define NT 512

typedef short v8s __attribute__((ext_vector_type(8)));
typedef _Float16 v8h __attribute__((ext_vector_type(8)));
typedef float f32x4 __attribute__((ext_vector_type(4)));
typedef float f32x16 __attribute__((ext_vector_type(16)));

// ---- static device buffers: referenced ONLY inside device code. ----
// +4096 pad: knn_mfma/agg_mfma read rows u=20..31 of the last samples (garbage,
// multiplied by zero-padded M columns / never stored).
#define NELEM ((size_t)BB * P * 320)          // 209.7 MB each
__device__ unsigned int g_C[3][P * P];
__device__ __align__(16) unsigned short g_bufA[NELEM + 4096];  // z1 / y2(bf16) / y3(bf16) / h4
__device__ __align__(16) unsigned short g_bufB[NELEM + 4096];  // h1 / h2 / h3f
__device__ __align__(16) unsigned short g_W1b[320 * 128];
__device__ __align__(16) unsigned short g_W2b[128 * 320];
__device__ __align__(16) unsigned short g_W3b[64 * 128];
__device__ __align__(16) unsigned short g_W4b[112 * 1024];
__device__ __align__(16) float g_b1p[320];
__device__ __align__(16) float g_b2p[128];
__device__ __align__(16) float g_b3p[64];
__device__ __align__(16) float g_b4p[112];

__device__ inline float bf2f(unsigned short u) {
    union { unsigned int i; float f; } c; c.i = ((unsigned int)u) << 16; return c.f;
}
__device__ inline unsigned short f2bf(float f) {
    union { float f; unsigned int i; } c; c.f = f;
    unsigned int u = c.i + 0x7fffu + ((c.i >> 16) & 1u);  // RNE (no NaN in data)
    return (unsigned short)(u >> 16);
}

// Pad+convert weights/biases to bf16 (zero pads -> pad outputs relu(0+0)=0).
// Also zeroes g_C (merged former zero_C launch — runs before any knn kernel).
__global__ void prep_kernel(const float* __restrict__ W1, const float* __restrict__ b1,
                            const float* __restrict__ W2, const float* __restrict__ b2,
                            const float* __restrict__ W3, const float* __restrict__ b3,
                            const float* __restrict__ W4, const float* __restrict__ b4) {
    const int stride = gridDim.x * blockDim.x;
    const int id = blockIdx.x * blockDim.x + threadIdx.x;
    for (int i = id; i < 3 * P * P; i += stride) g_C[i / (P * P)][i % (P * P)] = 0u;
    for (int i = id; i < 320 * 128; i += stride) { int n = i >> 7, k = i & 127;
        g_W1b[i] = (n < 300) ? f2bf(W1[n * 128 + k]) : 0; }
    for (int i = id; i < 128 * 320; i += stride) { int n = i / 320, k = i - n * 320;
        g_W2b[i] = (n < 100 && k < 300) ? f2bf(W2[n * 300 + k]) : 0; }
    for (int i = id; i < 64 * 128; i += stride) { int n = i >> 7, k = i & 127;
        g_W3b[i] = (n < 50 && k < 100) ? f2bf(W3[n * 100 + k]) : 0; }
    for (int i = id; i < 112 * 1024; i += stride) { int n = i >> 10, k = i & 1023;
        g_W4b[i] = (n < 100 && k < 1000) ? f2bf(W4[n * 1000 + k]) : 0; }
    for (int i = id; i < 320; i += stride) g_b1p[i] = (i < 300) ? b1[i] : 0.f;
    for (int i = id; i < 128; i += stride) g_b2p[i] = (i < 100) ? b2[i] : 0.f;
    for (int i = id; i < 64;  i += stride) g_b3p[i] = (i < 50)  ? b3[i] : 0.f;
    for (int i = id; i < 112; i += stride) g_b4p[i] = (i < 100) ? b4[i] : 0.f;
}

// ---- per-lane register top-k (verified r6/r8 tie-break order), histogram
// into the wave's PRIVATE hist (lane p is the sole writer of its column ->
// plain adds, no atomics, no barriers).
__device__ inline void topk_to_hist(const float* G, unsigned int* histw, int lane) {
    if (lane < P) {
        const int p = lane;
        float d2[P];
        const float gpp = G[p * 21 + p];
#pragma unroll
        for (int u = 0; u < P; ++u)
            d2[u] = (u == p) ? 0.f : gpp + G[u * 21 + u] - 2.f * G[p * 21 + u];
        float pv = -3.0e38f; int pi = -1;
        for (int it = 0; it < 6; ++it) {
            float best = 3.0e38f; int bq = 0;
#pragma unroll
            for (int u = 0; u < P; ++u) {
                float vu = d2[u];
                bool cand = (vu > pv) || (vu == pv && u > pi);
                if (cand && vu < best) { best = vu; bq = u; }
            }
            if (it > 0) histw[bq * P + p] += 1u;
            pv = best; pi = bq;
        }
    }
}

// ---------------- kNN layer 1 (round-23: barrier-free convoy fix) -----------
// r16 counters: Occupancy 81% yet VALUBusy 23%, BW 742 GB/s -> block barriers
// convoy 8 waves behind each wave's ~500cy dependent topk chain. Fix: Gs is
// already per-wave; make hist per-wave too -> NO block barriers in the pass
// loop (wave_barrier = compiler fence only; same-wave DS ops are processed
// in order by HW). One __syncthreads at the end + 8-way reduction. Topk math
// untouched -> C0 bit-identical.
__global__ __launch_bounds__(NT)
void knn1_mfma_kernel(const float* __restrict__ x) {
    __shared__ float Gs[8][P * 21];
    __shared__ unsigned int hist[8][P * P];
    const int t = threadIdx.x, w = t >> 6, lane = t & 63;
    const int m31 = lane & 31, half = lane >> 5;
    const int mrow = (m31 < P) ? m31 : (P - 1);
    for (int i = lane; i < P * P; i += 64) hist[w][i] = 0;   // own wave's hist
    for (int pass = 0; pass < 2; ++pass) {
        const size_t s = (size_t)blockIdx.x * 16 + pass * 8 + w;
        const float* rp = x + s * (size_t)(P * 128) + (size_t)mrow * 128 + half * 8;
        f32x16 acc;
#pragma unroll
        for (int i = 0; i < 16; ++i) acc[i] = 0.f;
#pragma unroll
        for (int ks = 0; ks < 8; ++ks) {
            float4 f0 = *(const float4*)(rp + ks * 16);
            float4 f1 = *(const float4*)(rp + ks * 16 + 4);
            float fv[8] = {f0.x, f0.y, f0.z, f0.w, f1.x, f1.y, f1.z, f1.w};
            v8h hi, lo;
#pragma unroll
            for (int j = 0; j < 8; ++j) {
                _Float16 hv = (_Float16)fv[j];
                hi[j] = hv;
                lo[j] = (_Float16)(fv[j] - (float)hv);
            }
            acc = __builtin_amdgcn_mfma_f32_32x32x16_f16(hi, hi, acc, 0, 0, 0);
            acc = __builtin_amdgcn_mfma_f32_32x32x16_f16(hi, lo, acc, 0, 0, 0);
            acc = __builtin_amdgcn_mfma_f32_32x32x16_f16(lo, hi, acc, 0, 0, 0);
            acc = __builtin_amdgcn_mfma_f32_32x32x16_f16(lo, lo, acc, 0, 0, 0);
        }
        float* G = &Gs[w][0];
        if (m31 < P) {
#pragma unroll
            for (int r = 0; r < 16; ++r) {
                int row = (r & 3) + 8 * (r >> 2) + 4 * half;
                if (row < P) G[row * 21 + m31] = acc[r];
            }
        }
        __builtin_amdgcn_wave_barrier();     // order same-wave LDS W->R
        topk_to_hist(G, &hist[w][0], lane);
        __builtin_amdgcn_wave_barrier();
    }
    __syncthreads();
    for (int i = t; i < P * P; i += NT) {
        unsigned int sum = 0;
#pragma unroll
        for (int ww = 0; ww < 8; ++ww) sum += hist[ww][i];
        if (sum) atomicAdd(&g_C[0][i], sum);
    }
}

// ---------------- kNN via MFMA Gram, barrier-free (round-23) ----------------
template<int D, int CIDX>
__global__ __launch_bounds__(NT)
void knn_mfma_kernel() {
    __shared__ float Gs[8][P * 21];
    __shared__ unsigned int hist[8][P * P];
    const int t = threadIdx.x, w = t >> 6, lane = t & 63;
    const int m31 = lane & 31, half = lane >> 5;
    for (int i = lane; i < P * P; i += 64) hist[w][i] = 0;   // own wave's hist
    for (int pass = 0; pass < 2; ++pass) {
        const size_t s = (size_t)blockIdx.x * 16 + pass * 8 + w;
        const unsigned short* rp = g_bufB + s * (P * D) + (size_t)m31 * D + half * 8;
        f32x16 acc;
#pragma unroll
        for (int i = 0; i < 16; ++i) acc[i] = 0.f;
        for (int ks = 0; ks < D / 16; ++ks) {
            v8s z = *(const v8s*)(rp + ks * 16);
            acc = __builtin_amdgcn_mfma_f32_32x32x16_bf16(z, z, acc, 0, 0, 0);
        }
        float* G = &Gs[w][0];
        if (m31 < P) {
#pragma unroll
            for (int r = 0; r < 16; ++r) {
                int row = (r & 3) + 8 * (r >> 2) + 4 * half;
                if (row < P) G[row * 21 + m31] = acc[r];
            }
        }
        __builtin_amdgcn_wave_barrier();     // order same-wave LDS W->R
        topk_to_hist(G, &hist[w][0], lane);
        __builtin_amdgcn_wave_barrier();
    }
    __syncthreads();
    for (int i = t; i < P * P; i += NT) {
        unsigned int sum = 0;
#pragma unroll
        for (int ww = 0; ww < 8; ++ww) sum += hist[ww][i];
        if (sum) atomicAdd(&g_C[CIDX][i], sum);
    }
}

// compute_M for 512-thread blocks (strided loops)
__device__ inline void compute_M_512(const unsigned int* __restrict__ Cg,
                                     float* Ms, float* dinv, int t) {
    for (int i = t; i < P * P; i += 512) Ms[i] = (float)Cg[i];
    __syncthreads();
    if (t < P) {
        float deg = 1.f;
        for (int u = 0; u < P; ++u) deg += Ms[t * P + u];
        dinv[t] = 1.f / sqrtf(deg);
    }
    __syncthreads();
    for (int i = t; i < P * P; i += 512) {
        int v = i / P, u = i - v * P;
        float m = dinv[v] * Ms[i] * dinv[u];
        if (v == u) m += dinv[v] * dinv[v];
        Ms[i] = m;
    }
    __syncthreads();
}

// ---------------- agg via MFMA (verified r13): z1 = M @ x, layer 1 only -----
template<int D, int CIDX>
__global__ __launch_bounds__(512)
void agg_mfma_kernel(const float* __restrict__ xin) {
    constexpr int NCB = D / 32;              // 32-col blocks
    __shared__ float Ms[P * P];
    __shared__ float dinv[P];
    const int t = threadIdx.x, w = t >> 6, lane = t & 63;
    const int n31 = lane & 31, half = lane >> 5;
    compute_M_512(g_C[CIDX], Ms, dinv, t);
    v8s mhi[2], mlo[2];
#pragma unroll
    for (int kc = 0; kc < 2; ++kc)
#pragma unroll
        for (int j = 0; j < 8; ++j) {
            const int u = kc * 16 + half * 8 + j;
            const int v = n31;
            const float m = (v < P && u < P) ? Ms[v * P + u] : 0.f;
            const unsigned short h16 = f2bf(m);
            mhi[kc][j] = (short)h16;
            mlo[kc][j] = (short)f2bf(m - bf2f(h16));
        }
    const size_t s = (size_t)blockIdx.x * 8 + w;
    unsigned short* zout = g_bufA + s * (size_t)(P * D);
    const float* xr = xin + s * (size_t)(P * D);
#pragma unroll
    for (int cb = 0; cb < NCB; ++cb) {
        v8s bh0, bl0, bh1, bl1;
#pragma unroll
        for (int j = 0; j < 8; ++j) {
            const int u0 = half * 8 + j;                 // < 16, always valid
            int u1 = 16 + half * 8 + j; if (u1 > P - 1) u1 = P - 1;  // clamp
            const float x0 = xr[(size_t)u0 * D + cb * 32 + n31];
            const float x1 = xr[(size_t)u1 * D + cb * 32 + n31];
            const unsigned short h0 = f2bf(x0), h1 = f2bf(x1);
            bh0[j] = (short)h0; bl0[j] = (short)f2bf(x0 - bf2f(h0));
            bh1[j] = (short)h1; bl1[j] = (short)f2bf(x1 - bf2f(h1));
        }
        f32x16 acc;
#pragma unroll
        for (int i = 0; i < 16; ++i) acc[i] = 0.f;
        acc = __builtin_amdgcn_mfma_f32_32x32x16_bf16(mhi[0], bh0, acc, 0, 0, 0);
        acc = __builtin_amdgcn_mfma_f32_32x32x16_bf16(mhi[0], bl0, acc, 0, 0, 0);
        acc = __builtin_amdgcn_mfma_f32_32x32x16_bf16(mlo[0], bh0, acc, 0, 0, 0);
        acc = __builtin_amdgcn_mfma_f32_32x32x16_bf16(mlo[0], bl0, acc, 0, 0, 0);
        acc = __builtin_amdgcn_mfma_f32_32x32x16_bf16(mhi[1], bh1, acc, 0, 0, 0);
        acc = __builtin_amdgcn_mfma_f32_32x32x16_bf16(mhi[1], bl1, acc, 0, 0, 0);
        acc = __builtin_amdgcn_mfma_f32_32x32x16_bf16(mlo[1], bh1, acc, 0, 0, 0);
        acc = __builtin_amdgcn_mfma_f32_32x32x16_bf16(mlo[1], bl1, acc, 0, 0, 0);
#pragma unroll
        for (int r = 0; r < 16; ++r) {
            const int row = (r & 3) + 8 * (r >> 2) + 4 * half;
            if (row < P)
                zout[(size_t)row * D + cb * 32 + n31] = f2bf(acc[r]);
        }
    }
}

// ---------------- agg-after-gemm, bf16 y (verified r18) ---------------------
template<int D, int CIDX, bool FLATOUT>
__global__ __launch_bounds__(512)
void agg_out_kernel() {
    constexpr int NCB = D / 32;
    __shared__ float Ms[P * P];
    __shared__ float dinv[P];
    const int t = threadIdx.x, w = t >> 6, lane = t & 63;
    const int n31 = lane & 31, half = lane >> 5;
    const float* __restrict__ bp = (CIDX == 1) ? g_b2p : g_b3p;
    compute_M_512(g_C[CIDX], Ms, dinv, t);
    v8s mhi[2], mlo[2];
#pragma unroll
    for (int kc = 0; kc < 2; ++kc)
#pragma unroll
        for (int j = 0; j < 8; ++j) {
            const int u = kc * 16 + half * 8 + j;
            const int v = n31;
            const float m = (v < P && u < P) ? Ms[v * P + u] : 0.f;
            const unsigned short h16 = f2bf(m);
            mhi[kc][j] = (short)h16;
            mlo[kc][j] = (short)f2bf(m - bf2f(h16));
        }
    const size_t s = (size_t)blockIdx.x * 8 + w;
    const unsigned short* yr = g_bufA + s * (size_t)(P * D);
#pragma unroll
    for (int cb = 0; cb < NCB; ++cb) {
        v8s b0, b1;
#pragma unroll
        for (int j = 0; j < 8; ++j) {
            const int u0 = half * 8 + j;                 // < 16, always valid
            int u1 = 16 + half * 8 + j; if (u1 > P - 1) u1 = P - 1;  // clamp
            b0[j] = (short)yr[(size_t)u0 * D + cb * 32 + n31];
            b1[j] = (short)yr[(size_t)u1 * D + cb * 32 + n31];
        }
        f32x16 acc;
#pragma unroll
        for (int i = 0; i < 16; ++i) acc[i] = 0.f;
        acc = __builtin_amdgcn_mfma_f32_32x32x16_bf16(mhi[0], b0, acc, 0, 0, 0);
        acc = __builtin_amdgcn_mfma_f32_32x32x16_bf16(mlo[0], b0, acc, 0, 0, 0);
        acc = __builtin_amdgcn_mfma_f32_32x32x16_bf16(mhi[1], b1, acc, 0, 0, 0);
        acc = __builtin_amdgcn_mfma_f32_32x32x16_bf16(mlo[1], b1, acc, 0, 0, 0);
        const float bv = bp[cb * 32 + n31];
#pragma unroll
        for (int r = 0; r < 16; ++r) {
            const int row = (r & 3) + 8 * (r >> 2) + 4 * half;
            if (row < P) {
                const float val = fmaxf(acc[r] + bv, 0.f);
                if (FLATOUT) {
                    const int d = cb * 32 + n31;
                    if (d < 50)
                        g_bufB[s * 1024 + (size_t)row * 50 + d] = f2bf(val);
                } else {
                    g_bufB[(s * (size_t)P + row) * D + cb * 32 + n31] = f2bf(val);
                }
            }
        }
    }
}

// ---------------- gemm2' (r14 structure): y2 = h1 @ W2^T, bf16 raw out ------
__global__ __launch_bounds__(256)
void gemm2_kernel() {
    constexpr int KL = 72;                   // padded LDS row, elems
    __shared__ __align__(16) unsigned short As[128 * KL];
    __shared__ __align__(16) unsigned short Wsh[128 * KL];
    const int t = threadIdx.x, w = t >> 6, lane = t & 63;
    const int m15 = lane & 15, q = lane >> 4;
    const long row0 = (long)blockIdx.x * 128;
    f32x4 acc[2][8];
#pragma unroll
    for (int zr = 0; zr < 2; ++zr)
#pragma unroll
        for (int nf = 0; nf < 8; ++nf) acc[zr][nf] = 0.f;
    for (int kc = 0; kc < 5; ++kc) {         // K chunks of 64 elems
        __syncthreads();                     // guard LDS reuse
        for (int i = t; i < 1024; i += 256) {
            const int r = i >> 3, c8 = i & 7;
            *(v8s*)&As[r * KL + c8 * 8] =
                *(const v8s*)(g_bufB + (size_t)(row0 + r) * 320 + kc * 64 + c8 * 8);
            *(v8s*)&Wsh[r * KL + c8 * 8] =
                *(const v8s*)(g_W2b + (size_t)r * 320 + kc * 64 + c8 * 8);
        }
        __syncthreads();
#pragma unroll
        for (int ks = 0; ks < 2; ++ks) {     // 32-elem MFMA sub-steps
            v8s af[2];
#pragma unroll
            for (int zr = 0; zr < 2; ++zr)
                af[zr] = *(const v8s*)&As[(w * 32 + zr * 16 + m15) * KL + ks * 32 + q * 8];
#pragma unroll
            for (int nf = 0; nf < 8; ++nf) {
                v8s wf = *(const v8s*)&Wsh[(nf * 16 + m15) * KL + ks * 32 + q * 8];
#pragma unroll
                for (int zr = 0; zr < 2; ++zr)
                    acc[zr][nf] = __builtin_amdgcn_mfma_f32_16x16x32_bf16(
                        wf, af[zr], acc[zr][nf], 0, 0, 0);
            }
        }
    }
#pragma unroll
    for (int zr = 0; zr < 2; ++zr) {
        const long m = row0 + w * 32 + zr * 16 + m15;
#pragma unroll
        for (int nf = 0; nf < 8; ++nf) {
            f32x4 c = acc[zr][nf];
            ushort4 o; o.x = f2bf(c[0]); o.y = f2bf(c[1]);
            o.z = f2bf(c[2]); o.w = f2bf(c[3]);
            *(ushort4*)(g_bufA + (size_t)m * 128 + nf * 16 + q * 4) = o;
        }
    }
}

// ---------------- streaming MFMA GEMM (r9 form; + RAWBF16 raw-bf16 out) -----
template<int Kp, int Np, int ZR, bool FLAT, int WSEL, bool ATOB, int NSPLIT,
         int KSC, int NTHR, long MROWS, bool RAWBF16>
__global__ __launch_bounds__(NTHR)
void gemm_kernel() {
    constexpr int BN = Np / NSPLIT;          // cols handled by this block
    constexpr int NF = BN / 16;
    constexpr int KS = Kp / 32;
    constexpr int CPT = KS / KSC;            // chunks per tile
    constexpr int KL = Kp + 8;               // padded LDS row (elems, 16B step)
    constexpr int NW = NTHR / 64;
    constexpr int TM = NW * ZR * 16;         // rows per tile
    constexpr long NTILE = MROWS / TM;
    static_assert(KS % KSC == 0, "KSC must divide KS");
    __shared__ __align__(16) unsigned short Ws[BN * KL];
    __shared__ __align__(16) float bs[BN];
    const unsigned short* __restrict__ Wb =
        (WSEL == 1) ? g_W1b : (WSEL == 2) ? g_W2b : (WSEL == 3) ? g_W3b : g_W4b;
    const float* __restrict__ bp =
        (WSEL == 1) ? g_b1p : (WSEL == 2) ? g_b2p : (WSEL == 3) ? g_b3p : g_b4p;
    const unsigned short* __restrict__ A = ATOB ? g_bufA : g_bufB;
    unsigned short* __restrict__ Hout = ATOB ? g_bufB : g_bufA;
    const int t = threadIdx.x, w = t >> 6, lane = t & 63;
    const int m15 = lane & 15, q = lane >> 4;
    const int n0 = blockIdx.y * BN;
    // ---- stage W slice + bias to LDS (once per block) ----
    for (int i = t; i < BN * (Kp / 8); i += NTHR) {
        int r = i / (Kp / 8), c = i - r * (Kp / 8);
        *(v8s*)(&Ws[r * KL + c * 8]) = *(const v8s*)(Wb + (size_t)(n0 + r) * Kp + c * 8);
    }
    for (int i = t; i < BN; i += NTHR) bs[i] = bp[n0 + i];
    __syncthreads();

    v8s aC[ZR][KSC], aN[ZR][KSC];
    long tile = (long)blockIdx.x;
    if (tile < NTILE) {
        const unsigned short* ab =
            A + (size_t)(tile * TM + w * (ZR * 16) + m15) * Kp + q * 8;
#pragma unroll
        for (int zr = 0; zr < ZR; ++zr)
#pragma unroll
            for (int ks = 0; ks < KSC; ++ks)
                aC[zr][ks] = *(const v8s*)(ab + (size_t)zr * 16 * Kp + ks * 32);
    }
    for (; tile < NTILE; tile += gridDim.x) {
        f32x4 acc[ZR][NF];
#pragma unroll
        for (int zr = 0; zr < ZR; ++zr)
#pragma unroll
            for (int nf = 0; nf < NF; ++nf) acc[zr][nf] = 0.f;
        for (int c = 0; c < CPT; ++c) {
            // issue next chunk's A loads before consuming the current chunk
            const long ntile = (c + 1 < CPT) ? tile : tile + (long)gridDim.x;
            const int nk0 = (c + 1 < CPT) ? (c + 1) * KSC : 0;
            const bool hasNext = (ntile < NTILE);
            if (hasNext) {
                const unsigned short* ab =
                    A + (size_t)(ntile * TM + w * (ZR * 16) + m15) * Kp + nk0 * 32 + q * 8;
#pragma unroll
                for (int zr = 0; zr < ZR; ++zr)
#pragma unroll
                    for (int ks = 0; ks < KSC; ++ks)
                        aN[zr][ks] = *(const v8s*)(ab + (size_t)zr * 16 * Kp + ks * 32);
            }
#pragma unroll
            for (int nf = 0; nf < NF; ++nf) {
                v8s wr[KSC];
#pragma unroll
                for (int ks = 0; ks < KSC; ++ks)
                    wr[ks] = *(const v8s*)(&Ws[(nf * 16 + m15) * KL + (c * KSC + ks) * 32 + q * 8]);
#pragma unroll
                for (int ks = 0; ks < KSC; ++ks)
#pragma unroll
                    for (int zr = 0; zr < ZR; ++zr)
                        acc[zr][nf] = __builtin_amdgcn_mfma_f32_16x16x32_bf16(
                            wr[ks], aC[zr][ks], acc[zr][nf], 0, 0, 0);
            }
            if (hasNext) {
#pragma unroll
                for (int zr = 0; zr < ZR; ++zr)
#pragma unroll
                    for (int ks = 0; ks < KSC; ++ks) aC[zr][ks] = aN[zr][ks];
            }
        }
        // ---- epilogue ----
#pragma unroll
        for (int zr = 0; zr < ZR; ++zr) {
            const long m = tile * TM + w * (ZR * 16) + zr * 16 + m15;
#pragma unroll
            for (int nf = 0; nf < NF; ++nf) {
                f32x4 cc = acc[zr][nf];
                if (RAWBF16) {
                    ushort4 o; o.x = f2bf(cc[0]); o.y = f2bf(cc[1]);
                    o.z = f2bf(cc[2]); o.w = f2bf(cc[3]);
                    *(ushort4*)(Hout + (size_t)m * Np + n0 + nf * 16 + q * 4) = o;
                } else {
                    f32x4 b4 = *(const f32x4*)(&bs[nf * 16 + q * 4]);
                    float v0 = fmaxf(cc[0] + b4[0], 0.f), v1 = fmaxf(cc[1] + b4[1], 0.f);
                    float v2 = fmaxf(cc[2] + b4[2], 0.f), v3 = fmaxf(cc[3] + b4[3], 0.f);
                    if (!FLAT) {
                        ushort4 o; o.x = f2bf(v0); o.y = f2bf(v1); o.z = f2bf(v2); o.w = f2bf(v3);
                        *(ushort4*)(Hout + (size_t)m * Np + n0 + nf * 16 + q * 4) = o;
                    } else {
                        const int n0f = nf * 16 + q * 4;   // FLAT only with NSPLIT=1
                        if (n0f <= 48) {
                            const long s = m / 20; const int u = (int)(m - s * 20);
                            unsigned short* base = Hout + (size_t)s * 1024 + u * 50 + n0f;
                            unsigned int lo = (unsigned int)f2bf(v0) | ((unsigned int)f2bf(v1) << 16);
                            *(unsigned int*)(base) = lo;
                            if (n0f < 48) {
                                unsigned int hi = (unsigned int)f2bf(v2) | ((unsigned int)f2bf(v3) << 16);
                                *(unsigned int*)(base + 2) = hi;
                            }
                        }
                    }
                }
            }
        }
    }
}

// logits = W5 h4 + b5; softmax -> out. h4 in g_bufA (112-padded rows).
// 256 blocks x 64 threads -> 4x CU coverage (verified r20). One sample/thread.
__global__ __launch_bounds__(64)
void head_kernel(const float* __restrict__ W5, const float* __restrict__ b5,
                 float* __restrict__ out) {
    __shared__ float w5s[300];
    __shared__ float b5s[3];
    const int t = threadIdx.x;
    for (int i = t; i < 300; i += 64) w5s[i] = W5[i];
    if (t < 3) b5s[t] = b5[t];
    __syncthreads();
    const int s = blockIdx.x * 64 + t;
    const unsigned short* h = g_bufA + (size_t)s * 112;
    float a0 = b5s[0], a1 = b5s[1], a2 = b5s[2];
    for (int k = 0; k < 100; ++k) {
        float hv = bf2f(h[k]);
        a0 += hv * w5s[k]; a1 += hv * w5s[100 + k]; a2 += hv * w5s[200 + k];
    }
    float m = fmaxf(a0, fmaxf(a1, a2));
    float e0 = expf(a0 - m), e1 = expf(a1 - m), e2 = expf(a2 - m);
    float inv = 1.f / (e0 + e1 + e2);
    out[(size_t)s * 3 + 0] = e0 * inv;
    out[(size_t)s * 3 + 1] = e1 * inv;
    out[(size_t)s * 3 + 2] = e2 * inv;
}

extern "C" void kernel_launch(void* const* d_in, const int* in_sizes, int n_in,
                              void* d_out, int out_size, void* d_ws, size_t ws_size,
                              hipStream_t stream) {
    const float* x  = (const float*)d_in[0];
    const float* W1 = (const float*)d_in[1];
    const float* b1 = (const float*)d_in[2];
    const float* W2 = (const float*)d_in[3];
    const float* b2 = (const float*)d_in[4];
    const float* W3 = (const float*)d_in[5];
    const float* b3 = (const float*)d_in[6];
    const float* W4 = (const float*)d_in[7];
    const float* b4 = (const float*)d_in[8];
    const float* W5 = (const float*)d_in[9];
    const float* b5 = (const float*)d_in[10];
    float* out = (float*)d_out;

    prep_kernel<<<256, 256, 0, stream>>>(W1, b1, W2, b2, W3, b3, W4, b4);

    // ---- layer 1 ----
    knn1_mfma_kernel<<<BB / 16, NT, 0, stream>>>(x);                 // x -> C0
    agg_mfma_kernel<128, 0><<<BB / 8, 512, 0, stream>>>(x);          // x -> z1(A)
    gemm_kernel<128, 320, 1, false, 1, true, 2, 4, 512, 327680L, false>
        <<<dim3(1024, 2), 512, 0, stream>>>();                       // z1 -> h1(B)

    // ---- layer 2 (gemm first, bf16 y2; agg on y2) ----
    knn_mfma_kernel<320, 1><<<BB / 16, NT, 0, stream>>>();           // h1(B) -> C1
    gemm2_kernel<<<2560, 256, 0, stream>>>();                        // h1 -> y2 bf16 (A)
    agg_out_kernel<128, 1, false><<<BB / 8, 512, 0, stream>>>();     // y2 -> h2(B)

    // ---- layer 3 (gemm first, bf16 y3; agg on y3) ----
    knn_mfma_kernel<128, 2><<<BB / 16, NT, 0, stream>>>();           // h2(B) -> C2
    gemm_kernel<128, 64, 2, false, 3, false, 1, 4, 256, 327680L, true>
        <<<dim3(512, 1), 256, 0, stream>>>();                        // h2 -> y3 bf16 (A)
    agg_out_kernel<64, 2, true><<<BB / 8, 512, 0, stream>>>();       // y3 -> h3f(B) FLAT

    // ---- head MLP ----
    gemm_kernel<1024, 112, 1, false, 4, false, 7, 8, 256, 16384L, false>
        <<<dim3(256, 7), 256, 0, stream>>>();                        // h3f(B) -> h4(A)
    head_kernel<<<BB / 64, 64, 0, stream>>>(W5, b5, out);
}